// Round 8
// baseline (336.555 us; speedup 1.0000x reference)
//
#include <hip/hip_runtime.h>
#include <math.h>

// Problem constants (fixed by setup_inputs)
#define B_SZ 8
#define IMG_H 64
#define IMG_W 64
#define N_TOK 4096          // 64*64
#define C_DIM 512
#define HEADS 16
#define HDIM 32
#define M_ROWS (B_SZ * N_TOK)   // 32768
#define QK_COLS (2 * C_DIM)     // 1024

// theta coefficient: -ln(10000)/128
#define THETA_COEF (-0.07195578415606394f)

typedef __attribute__((ext_vector_type(8))) __bf16 bf16x8;
typedef __attribute__((ext_vector_type(4))) float f32x4;

__device__ __forceinline__ void async_ld16(void* lds, const void* g) {
    __builtin_amdgcn_global_load_lds(
        (const __attribute__((address_space(1))) unsigned*)g,
        (__attribute__((address_space(3))) unsigned*)lds, 16, 0, 0);
}

__device__ __forceinline__ unsigned short f2bf(float f) {
    unsigned u = __float_as_uint(f);
    u += 0x7FFF + ((u >> 16) & 1);   // round-to-nearest-even (finite inputs)
    return (unsigned short)(u >> 16);
}

// ---------------------------------------------------------------------------
// Pass 0 (merged): fp32->bf16 for x (blocks 0..16383) and Wqk (..16895),
// RoPE cos/sin LUT + rsp table (..16927).
// ---------------------------------------------------------------------------
__global__ __launch_bounds__(256) void prep_kernel(
    const float* __restrict__ x, const float* __restrict__ Wqk,
    const float* __restrict__ scale_p,
    unsigned short* __restrict__ xb, unsigned short* __restrict__ Wb,
    float* __restrict__ lut)
{
    int bid = blockIdx.x;
    int t = threadIdx.x;
    if (bid < 16384) {
        int i = bid * 256 + t;
        float4 v = ((const float4*)x)[i];
        ushort4 o;
        o.x = f2bf(v.x); o.y = f2bf(v.y); o.z = f2bf(v.z); o.w = f2bf(v.w);
        ((ushort4*)xb)[i] = o;
    } else if (bid < 16896) {
        int i = (bid - 16384) * 256 + t;
        float4 v = ((const float4*)Wqk)[i];
        ushort4 o;
        o.x = f2bf(v.x); o.y = f2bf(v.y); o.z = f2bf(v.z); o.w = f2bf(v.w);
        ((ushort4*)Wb)[i] = o;
    } else {
        int idx = (bid - 16896) * 256 + t;   // 8192
        int pos = idx >> 7, tt = idx & 127;
        float theta = expf((float)tt * THETA_COEF);
        float ang = (float)pos * theta;
        lut[idx] = cosf(ang);
        lut[idx + 8192] = sinf(ang);
        if (idx < 512) lut[16384 + idx] = 1.0f / log1pf(expf(scale_p[idx]));
    }
}

// ---------------------------------------------------------------------------
// Pass 1: qk = x @ W^T + b (bf16 MFMA), fused RoPE + (elu+1) + /softplus(scale)
// + FUSED NORM PARTIALS: per output row, accumulate s^2 and s^6 over this
// wave's 64 cols (16-lane butterfly), store to nrmP[8 partials/row] — no
// atomics; norm_fin sums them. Kills norm_kernel's 134 MB re-read.
// nrmP layout (aliases kvp, 1,048,576 floats): qp2|qp6|kp2|kp6, each
// [8 slots][32768 rows]; slot = ((n0>>7)&3)*2 + (wn>>6).
// ---------------------------------------------------------------------------
#define GBM 128
#define GBN 128
#define GBK 32

#define EPI_I(I, ACC, N2, N6) do {                                            \
    float cr = cI, sr = sI;                                                   \
    _Pragma("unroll")                                                         \
    for (int r = 0; r < 4; ++r) {                                             \
        int m = m0 + wm + (I) * 16 + quad * 4 + r;                            \
        float val = (ACC)[r] + bias;                                          \
        float oth = __shfl_xor(val, 1);                                       \
        float rot = is_im ? (val * cr + oth * sr) : (val * cr - oth * sr);    \
        rot = (rot > 0.f) ? (rot + 1.f) : __expf(rot);                        \
        float ov = rot * rspv;                                                \
        dst[(size_t)m * C_DIM + ch] = ov;                                     \
        float ox = ov * ov;                                                   \
        (N2)[r] += ox;                                                        \
        (N6)[r] += ox * ox * ox;                                              \
        float tc = cr * c1 - sr * s1, ts = sr * c1 + cr * s1;                 \
        cr = tc; sr = ts;                                                     \
    }                                                                         \
    float uc = cI * c16 - sI * s16, us = sI * c16 + cI * s16;                 \
    cI = uc; sI = us;                                                         \
} while (0)

#define EPI_J(J, A0, A1, A2, A3) do {                                         \
    int c = n0 + wn + (J) * 16 + l16;                                         \
    int ch = c & 511;                                                         \
    float bias = bqk[c];                                                      \
    float rspv = rsp[ch];                                                     \
    int tt = ch >> 1;                                                         \
    int tl = tt & 127;                                                        \
    float cI, sI, c1, s1, c16, s16;                                           \
    if (tt < 128) {      /* block-uniform branch; pos wave-uniform */         \
        int pos = ((m0 + wm) & (N_TOK - 1)) >> 6;                             \
        cI = lut[pos * 128 + tl]; sI = lut[pos * 128 + tl + 8192];            \
        c1 = 1.f; s1 = 0.f; c16 = 1.f; s16 = 0.f;                             \
    } else {             /* pos = I*16 + quad*4 + r: rotate from seeds */     \
        int pos0 = quad * 4;                                                  \
        cI = lut[pos0 * 128 + tl]; sI = lut[pos0 * 128 + tl + 8192];          \
        c1  = lut[128 + tl];       s1  = lut[128 + tl + 8192];                \
        c16 = lut[2048 + tl];      s16 = lut[2048 + tl + 8192];               \
    }                                                                         \
    float* dst = (c < C_DIM) ? qW : kW;                                       \
    EPI_I(0, A0, n2_0, n6_0); EPI_I(1, A1, n2_1, n6_1);                       \
    EPI_I(2, A2, n2_2, n6_2); EPI_I(3, A3, n2_3, n6_3);                       \
} while (0)

#define NRED(I, N2, N6) do {                                                  \
    f32x4 v2s, v6s;                                                           \
    _Pragma("unroll")                                                         \
    for (int r = 0; r < 4; ++r) {                                             \
        float a2 = (N2)[r], a6 = (N6)[r];                                     \
        a2 += __shfl_xor(a2, 1); a6 += __shfl_xor(a6, 1);                     \
        a2 += __shfl_xor(a2, 2); a6 += __shfl_xor(a6, 2);                     \
        a2 += __shfl_xor(a2, 4); a6 += __shfl_xor(a6, 4);                     \
        a2 += __shfl_xor(a2, 8); a6 += __shfl_xor(a6, 8);                     \
        v2s[r] = a2; v6s[r] = a6;                                             \
    }                                                                         \
    if (l16 == 0) {                                                           \
        int m = m0 + wm + (I) * 16 + quad * 4;                                \
        *(float4*)&np2[pslot * 32768 + m] = *(float4*)&v2s;                   \
        *(float4*)&np6[pslot * 32768 + m] = *(float4*)&v6s;                   \
    }                                                                         \
} while (0)

__global__ __launch_bounds__(256, 1) void gemm_mfma_kernel(
    const unsigned short* __restrict__ xb,   // (32768,512) bf16
    const unsigned short* __restrict__ Wb,   // (1024,512) bf16
    const float* __restrict__ bqk,           // (1024)
    const float* __restrict__ lut,           // cos/sin LUT + rsp table
    float* __restrict__ qW,                  // (32768,512)
    float* __restrict__ kW,                  // (32768,512)
    float* __restrict__ nrmP)                // norm partials (aliases kvp)
{
    __shared__ char lds[32768];

    const float* rsp = lut + 16384;

    const int t = threadIdx.x;
    const int wave = t >> 6;
    const int lane = t & 63;
    const int quad = lane >> 4;
    const int l16 = lane & 15;
    const int is_im = l16 & 1;

    const int flat = blockIdx.x + 8 * blockIdx.y;
    const int xcd = flat & 7;
    const int ii_ = flat >> 3;
    const int n0 = (ii_ & 7) * GBN;
    const int m0 = (xcd * 32 + (ii_ >> 3)) * GBM;

    const int wm = (wave >> 1) * 64;
    const int wn = (wave & 1) * 64;

    const int srow = t >> 2;
    const int sj = t & 3;

    f32x4 acc00 = {0.f,0.f,0.f,0.f}, acc01 = {0.f,0.f,0.f,0.f},
          acc02 = {0.f,0.f,0.f,0.f}, acc03 = {0.f,0.f,0.f,0.f},
          acc10 = {0.f,0.f,0.f,0.f}, acc11 = {0.f,0.f,0.f,0.f},
          acc12 = {0.f,0.f,0.f,0.f}, acc13 = {0.f,0.f,0.f,0.f},
          acc20 = {0.f,0.f,0.f,0.f}, acc21 = {0.f,0.f,0.f,0.f},
          acc22 = {0.f,0.f,0.f,0.f}, acc23 = {0.f,0.f,0.f,0.f},
          acc30 = {0.f,0.f,0.f,0.f}, acc31 = {0.f,0.f,0.f,0.f},
          acc32 = {0.f,0.f,0.f,0.f}, acc33 = {0.f,0.f,0.f,0.f};

    const int swz = (l16 >> 1) & 3;
    const int co = (quad ^ swz) * 16;

    auto stage = [&](int k0, int b) {
#pragma unroll
        for (int p = 0; p < 2; ++p) {
            int m = p * 64 + srow;
            int jp = sj ^ ((m >> 1) & 3);
            const unsigned short* ga = xb + (size_t)(m0 + m) * C_DIM + k0 + jp * 8;
            async_ld16(lds + b * 16384 + p * 4096 + wave * 1024, ga);
            const unsigned short* gb = Wb + (size_t)(n0 + m) * C_DIM + k0 + jp * 8;
            async_ld16(lds + b * 16384 + 8192 + p * 4096 + wave * 1024, gb);
        }
    };

    stage(0, 0);
    __syncthreads();
    int buf = 0;

    for (int k0 = 0; k0 < C_DIM; k0 += GBK) {
        if (k0 + GBK < C_DIM) stage(k0 + GBK, buf ^ 1);

        const char* As = lds + buf * 16384;
        const char* Bs = As + 8192;
        bf16x8 a0 = *(const bf16x8*)(As + (wm + 0 * 16 + l16) * 64 + co);
        bf16x8 a1 = *(const bf16x8*)(As + (wm + 1 * 16 + l16) * 64 + co);
        bf16x8 a2 = *(const bf16x8*)(As + (wm + 2 * 16 + l16) * 64 + co);
        bf16x8 a3 = *(const bf16x8*)(As + (wm + 3 * 16 + l16) * 64 + co);
        bf16x8 b0 = *(const bf16x8*)(Bs + (wn + 0 * 16 + l16) * 64 + co);
        bf16x8 b1 = *(const bf16x8*)(Bs + (wn + 1 * 16 + l16) * 64 + co);
        bf16x8 b2 = *(const bf16x8*)(Bs + (wn + 2 * 16 + l16) * 64 + co);
        bf16x8 b3 = *(const bf16x8*)(Bs + (wn + 3 * 16 + l16) * 64 + co);

        acc00 = __builtin_amdgcn_mfma_f32_16x16x32_bf16(a0, b0, acc00, 0, 0, 0);
        acc01 = __builtin_amdgcn_mfma_f32_16x16x32_bf16(a0, b1, acc01, 0, 0, 0);
        acc02 = __builtin_amdgcn_mfma_f32_16x16x32_bf16(a0, b2, acc02, 0, 0, 0);
        acc03 = __builtin_amdgcn_mfma_f32_16x16x32_bf16(a0, b3, acc03, 0, 0, 0);
        acc10 = __builtin_amdgcn_mfma_f32_16x16x32_bf16(a1, b0, acc10, 0, 0, 0);
        acc11 = __builtin_amdgcn_mfma_f32_16x16x32_bf16(a1, b1, acc11, 0, 0, 0);
        acc12 = __builtin_amdgcn_mfma_f32_16x16x32_bf16(a1, b2, acc12, 0, 0, 0);
        acc13 = __builtin_amdgcn_mfma_f32_16x16x32_bf16(a1, b3, acc13, 0, 0, 0);
        acc20 = __builtin_amdgcn_mfma_f32_16x16x32_bf16(a2, b0, acc20, 0, 0, 0);
        acc21 = __builtin_amdgcn_mfma_f32_16x16x32_bf16(a2, b1, acc21, 0, 0, 0);
        acc22 = __builtin_amdgcn_mfma_f32_16x16x32_bf16(a2, b2, acc22, 0, 0, 0);
        acc23 = __builtin_amdgcn_mfma_f32_16x16x32_bf16(a2, b3, acc23, 0, 0, 0);
        acc30 = __builtin_amdgcn_mfma_f32_16x16x32_bf16(a3, b0, acc30, 0, 0, 0);
        acc31 = __builtin_amdgcn_mfma_f32_16x16x32_bf16(a3, b1, acc31, 0, 0, 0);
        acc32 = __builtin_amdgcn_mfma_f32_16x16x32_bf16(a3, b2, acc32, 0, 0, 0);
        acc33 = __builtin_amdgcn_mfma_f32_16x16x32_bf16(a3, b3, acc33, 0, 0, 0);

        __syncthreads();
        buf ^= 1;
    }

    // epilogue + fused norm partials
    f32x4 n2_0 = {0.f,0.f,0.f,0.f}, n2_1 = {0.f,0.f,0.f,0.f},
          n2_2 = {0.f,0.f,0.f,0.f}, n2_3 = {0.f,0.f,0.f,0.f},
          n6_0 = {0.f,0.f,0.f,0.f}, n6_1 = {0.f,0.f,0.f,0.f},
          n6_2 = {0.f,0.f,0.f,0.f}, n6_3 = {0.f,0.f,0.f,0.f};

    EPI_J(0, acc00, acc10, acc20, acc30);
    EPI_J(1, acc01, acc11, acc21, acc31);
    EPI_J(2, acc02, acc12, acc22, acc32);
    EPI_J(3, acc03, acc13, acc23, acc33);

    const int pslot = ((n0 >> 7) & 3) * 2 + (wn >> 6);
    float* np2 = nrmP + ((n0 < C_DIM) ? 0 : 524288);
    float* np6 = np2 + 262144;
    NRED(0, n2_0, n6_0);
    NRED(1, n2_1, n6_1);
    NRED(2, n2_2, n6_2);
    NRED(3, n2_3, n6_3);
}

// ---------------------------------------------------------------------------
// Pass 2: finalize norms from partials: s = sqrt(sum2)/sqrt(sum6)
// ---------------------------------------------------------------------------
__global__ __launch_bounds__(256) void norm_fin_kernel(
    const float* __restrict__ nrmP, float* __restrict__ sq, float* __restrict__ sk)
{
    int m = blockIdx.x * 256 + threadIdx.x;   // grid 128
    float q2 = 0.f, q6 = 0.f, k2 = 0.f, k6 = 0.f;
#pragma unroll
    for (int p = 0; p < 8; ++p) {
        q2 += nrmP[p * 32768 + m];
        q6 += nrmP[262144 + p * 32768 + m];
        k2 += nrmP[524288 + p * 32768 + m];
        k6 += nrmP[786432 + p * 32768 + m];
    }
    sq[m] = sqrtf(q2) / sqrtf(q6);
    sk[m] = sqrtf(k2) / sqrtf(k6);
}

// ---------------------------------------------------------------------------
// Pass 3a: partial kv[d][e] = sum_n k_f[n,d]*v[n,e] and km[d] = sum_n k_f[n,d]
// ---------------------------------------------------------------------------
#define NSPLIT 8
#define ROWS_PER_SPLIT (N_TOK / NSPLIT)   // 512

__global__ __launch_bounds__(256) void kv_partial_kernel(
    const float* __restrict__ x, const float* __restrict__ kW,
    const float* __restrict__ sk,
    float* __restrict__ kvp, float* __restrict__ kmp)
{
    int g = blockIdx.x >> 3;       // (b*16+h)
    int split = blockIdx.x & 7;
    int b = g >> 4, h = g & 15;
    int n_start = split * ROWS_PER_SPLIT;

    __shared__ float smem[5120];
    float* kf = smem;
    float* vv = smem + 64 * 36;

    int t = threadIdx.x;
    int wave = t >> 6, lane = t & 63;
    int srow = t >> 3;
    int scol = (t & 7) * 4;
    int d0 = (lane >> 3) * 4;
    int e0 = (lane & 7) * 4;

    float acc[4][4] = {{0.f}};
    float4 kmacc = make_float4(0.f, 0.f, 0.f, 0.f);

    float4 kreg[2], vreg[2];
    float sreg[2];
#pragma unroll
    for (int h2 = 0; h2 < 2; ++h2) {
        int n = n_start + h2 * 32 + srow;
        size_t base = ((size_t)(b * N_TOK + n)) * C_DIM + h * HDIM + scol;
        kreg[h2] = *(const float4*)&kW[base];
        vreg[h2] = *(const float4*)&x[base];
        sreg[h2] = sk[b * N_TOK + n];
    }

    for (int tt = 0; tt < ROWS_PER_SPLIT / 64; ++tt) {
        __syncthreads();
#pragma unroll
        for (int h2 = 0; h2 < 2; ++h2) {
            int row = h2 * 32 + srow;
            float4 k4 = kreg[h2];
            float s = sreg[h2];
            float4 k3;
            k3.x = k4.x * k4.x * k4.x * s;
            k3.y = k4.y * k4.y * k4.y * s;
            k3.z = k4.z * k4.z * k4.z * s;
            k3.w = k4.w * k4.w * k4.w * s;
            *(float4*)&kf[row * 36 + scol] = k3;
            *(float4*)&vv[row * 36 + scol] = vreg[h2];
            kmacc.x += k3.x; kmacc.y += k3.y;
            kmacc.z += k3.z; kmacc.w += k3.w;
        }
        if (tt < ROWS_PER_SPLIT / 64 - 1) {
            int nb = n_start + (tt + 1) * 64;
#pragma unroll
            for (int h2 = 0; h2 < 2; ++h2) {
                int n = nb + h2 * 32 + srow;
                size_t base = ((size_t)(b * N_TOK + n)) * C_DIM + h * HDIM + scol;
                kreg[h2] = *(const float4*)&kW[base];
                vreg[h2] = *(const float4*)&x[base];
                sreg[h2] = sk[b * N_TOK + n];
            }
        }
        __syncthreads();

        const float* kfp = kf + (wave * 16) * 36 + d0;
        const float* vvp = vv + (wave * 16) * 36 + e0;
#pragma unroll
        for (int nn = 0; nn < 16; ++nn) {
            float4 k4 = *(const float4*)(kfp + nn * 36);
            float4 v4 = *(const float4*)(vvp + nn * 36);
            acc[0][0] += k4.x * v4.x; acc[0][1] += k4.x * v4.y;
            acc[0][2] += k4.x * v4.z; acc[0][3] += k4.x * v4.w;
            acc[1][0] += k4.y * v4.x; acc[1][1] += k4.y * v4.y;
            acc[1][2] += k4.y * v4.z; acc[1][3] += k4.y * v4.w;
            acc[2][0] += k4.z * v4.x; acc[2][1] += k4.z * v4.y;
            acc[2][2] += k4.z * v4.z; acc[2][3] += k4.z * v4.w;
            acc[3][0] += k4.w * v4.x; acc[3][1] += k4.w * v4.y;
            acc[3][2] += k4.w * v4.z; acc[3][3] += k4.w * v4.w;
        }
    }

    __syncthreads();
    float* red = smem;                 // [4][32*32] laid out d*32+e
    float* kmr = smem + 4096;          // [32][32]
#pragma unroll
    for (int di = 0; di < 4; ++di) {
        float4 v = make_float4(acc[di][0], acc[di][1], acc[di][2], acc[di][3]);
        *(float4*)&red[wave * 1024 + (d0 + di) * 32 + e0] = v;
    }
    *(float4*)&kmr[srow * 32 + scol] = kmacc;
    __syncthreads();

    size_t pbase = (size_t)blockIdx.x * 1024;
    for (int idx = t; idx < 1024; idx += 256) {
        float s = red[idx] + red[1024 + idx] + red[2048 + idx] + red[3072 + idx];
        kvp[pbase + idx] = s;
    }
    if (t < 32) {
        float s = 0.f;
#pragma unroll
        for (int r = 0; r < 32; ++r) s += kmr[r * 32 + t];
        kmp[blockIdx.x * 32 + t] = s;
    }
}

// Pass 3b: reduce the 8 splits; scale by 1/N. kv written TRANSPOSED [g][e][d].
__global__ __launch_bounds__(256) void kv_reduce_kernel(
    const float* __restrict__ kvp, const float* __restrict__ kmp,
    float* __restrict__ kv, float* __restrict__ km)
{
    int g = blockIdx.x;   // 128
    int t = threadIdx.x;
    for (int idx = t; idx < 1024; idx += 256) {
        float s = 0.f;
#pragma unroll
        for (int sp = 0; sp < NSPLIT; ++sp)
            s += kvp[((size_t)(g * NSPLIT + sp)) * 1024 + idx];
        int d = idx >> 5, e = idx & 31;
        kv[(size_t)g * 1024 + e * 32 + d] = s * (1.0f / 4096.0f);
    }
    if (t < 32) {
        float s = 0.f;
#pragma unroll
        for (int sp = 0; sp < NSPLIT; ++sp) s += kmp[(g * NSPLIT + sp) * 32 + t];
        km[g * 32 + t] = s * (1.0f / 4096.0f);
    }
}

// ---------------------------------------------------------------------------
// Pass 4 (FUSED attn + depthwise conv). v2: conv row loads software-pipelined
// 2-deep (named rowA/rowB, fully unrolled ki -> no scratch): load rows 0,1
// upfront, then compute(ki) overlaps load(ki+2). Covers the ~200cy L2 hit
// latency that left 45% of cycles idle in v1 (VALUBusy 55%, MfmaUtil 0).
// ---------------------------------------------------------------------------
#define LOADROW(KI, ROW) do {                                                 \
    int ii = i + (KI) - 2;                                                    \
    if (ii >= 0 && ii < IMG_H) {                                              \
        const float* xr = xbase + (size_t)ii * 64 * C_DIM;                    \
        _Pragma("unroll")                                                     \
        for (int jx = 0; jx < 8; ++jx) {                                      \
            int jj = j0 + jx - 2;                                             \
            ROW[jx] = (jj >= 0 && jj < IMG_W)                                 \
                          ? *(const float4*)(xr + (size_t)jj * C_DIM)         \
                          : make_float4(0.f, 0.f, 0.f, 0.f);                  \
        }                                                                     \
    } else {                                                                  \
        _Pragma("unroll")                                                     \
        for (int jx = 0; jx < 8; ++jx)                                        \
            ROW[jx] = make_float4(0.f, 0.f, 0.f, 0.f);                        \
    }                                                                         \
} while (0)

#define COMPROW(KI, ROW) do {                                                 \
    _Pragma("unroll")                                                         \
    for (int kj = 0; kj < 5; ++kj) {                                          \
        float4 w4 = *(const float4*)&wl[(KI) * 5 + kj][o4];                   \
        _Pragma("unroll")                                                     \
        for (int jo = 0; jo < 4; ++jo) {                                      \
            acc[jo].x += w4.x * ROW[jo + kj].x;                               \
            acc[jo].y += w4.y * ROW[jo + kj].y;                               \
            acc[jo].z += w4.z * ROW[jo + kj].z;                               \
            acc[jo].w += w4.w * ROW[jo + kj].w;                               \
        }                                                                     \
    }                                                                         \
} while (0)

__global__ __launch_bounds__(256) void attn_conv_kernel(
    const float* __restrict__ qW, const float* __restrict__ sq,
    const float* __restrict__ kvT, const float* __restrict__ km,
    const float* __restrict__ x, const float* __restrict__ w,
    const float* __restrict__ wbias, float* __restrict__ out)
{
    int g = blockIdx.x;           // b*16 + h
    int b = g >> 4, h = g & 15;
    int n0 = blockIdx.y * 128;

    __shared__ float qf[16][36];
    __shared__ float ob[128][34];   // attn results
    __shared__ float wl[25][32];

    int t = threadIdx.x;
    for (int idx = t; idx < 800; idx += 256) {   // conv weights, once
        int o = idx & 31, tap = idx >> 5;
        wl[tap][o] = w[o * 25 + tap];
    }

    int e = t & 15;               // e-lane (handles e and e+16)
    int nl = t >> 4;              // row within 16-row chunk
    int sd = e * 2;               // staging d-pair

    const float* kvg = kvT + (size_t)g * 1024;
    float4 kva[8], kvb[8], kmr[8];
#pragma unroll
    for (int j = 0; j < 8; ++j) {
        kva[j] = *(const float4*)&kvg[e * 32 + j * 4];
        kvb[j] = *(const float4*)&kvg[(e + 16) * 32 + j * 4];
        kmr[j] = *(const float4*)&km[g * 32 + j * 4];
    }

    size_t rbase = ((size_t)(b * N_TOK + n0 + nl)) * C_DIM + h * HDIM;

    float2 q2 = *(const float2*)&qW[rbase + sd];
    float sv = sq[b * N_TOK + n0 + nl];

    for (int ch = 0; ch < 8; ++ch) {
        __syncthreads();          // previous chunk's qf reads done
        *(float2*)&qf[nl][sd] =
            make_float2(q2.x * q2.x * q2.x * sv, q2.y * q2.y * q2.y * sv);

        float2 q2n; float svn;
        if (ch < 7) {
            size_t nb = rbase + (size_t)(ch + 1) * 16 * C_DIM;
            q2n = *(const float2*)&qW[nb + sd];
            svn = sq[b * N_TOK + n0 + (ch + 1) * 16 + nl];
        }
        __syncthreads();          // staging visible

        float s1a = 0.f, s1b = 0.f, s2 = 0.f;
#pragma unroll
        for (int j = 0; j < 8; ++j) {
            float4 q4 = *(const float4*)&qf[nl][j * 4];
            s1a += q4.x * kva[j].x + q4.y * kva[j].y
                 + q4.z * kva[j].z + q4.w * kva[j].w;
            s1b += q4.x * kvb[j].x + q4.y * kvb[j].y
                 + q4.z * kvb[j].z + q4.w * kvb[j].w;
            s2  += q4.x * kmr[j].x + q4.y * kmr[j].y
                 + q4.z * kmr[j].z + q4.w * kmr[j].w;
        }
        float z = 1.0f / (s2 + 1e-6f);
        ob[ch * 16 + nl][e] = s1a * z;
        ob[ch * 16 + nl][e + 16] = s1b * z;

        if (ch < 7) { q2 = q2n; sv = svn; }
    }

    __syncthreads();              // ob + wl complete

    // ---- Phase B: depthwise conv 5x5, 2-deep pipelined row loads ----
    int r = t >> 7;               // image row within block (wave-uniform)
    int jg = (t >> 3) & 15;       // j-group of 4
    int cg = t & 7;               // channel-group of 4 (within head)
    int j0 = jg * 4;
    int o4 = cg * 4;
    int i = (n0 >> 6) + r;        // global image row

    const float* xbase = x + ((size_t)b * N_TOK) * C_DIM + h * HDIM + o4;

    float4 b4 = *(const float4*)&wbias[o4];
    float4 acc[4] = {b4, b4, b4, b4};

    float4 rowA[8], rowB[8];
    LOADROW(0, rowA);
    LOADROW(1, rowB);
    COMPROW(0, rowA); LOADROW(2, rowA);
    COMPROW(1, rowB); LOADROW(3, rowB);
    COMPROW(2, rowA); LOADROW(4, rowA);
    COMPROW(3, rowB);
    COMPROW(4, rowA);

    float* op = out + ((size_t)(b * N_TOK + i * 64 + j0)) * C_DIM + h * HDIM + o4;
#pragma unroll
    for (int jo = 0; jo < 4; ++jo) {
        float4 a = *(const float4*)&ob[r * 64 + j0 + jo][o4];
        acc[jo].x += a.x;
        acc[jo].y += a.y;
        acc[jo].z += a.z;
        acc[jo].w += a.w;
        *(float4*)(op + (size_t)jo * C_DIM) = acc[jo];
    }
}

// ---------------------------------------------------------------------------
extern "C" void kernel_launch(void* const* d_in, const int* in_sizes, int n_in,
                              void* d_out, int out_size, void* d_ws, size_t ws_size,
                              hipStream_t stream) {
    const float* x       = (const float*)d_in[0];
    const float* Wqk     = (const float*)d_in[1];
    const float* bqk     = (const float*)d_in[2];
    const float* scale_p = (const float*)d_in[3];
    const float* dwc_w   = (const float*)d_in[4];
    const float* dwc_b   = (const float*)d_in[5];
    float* out = (float*)d_out;
    float* ws = (float*)d_ws;

    // workspace layout (floats): qW | sq | sk | kvp | kmp | kv | km | xb | Wb | lut
    float* qW  = ws;                                  // 16,777,216
    float* sq  = qW + (size_t)M_ROWS * C_DIM;         // 32,768
    float* sk  = sq + M_ROWS;                         // 32,768
    float* kvp = sk + M_ROWS;                         // 1,048,576
    float* kmp = kvp + (size_t)1024 * 1024;           // 32,768
    float* kv  = kmp + 1024 * 32;                     // 131,072 (transposed [g][e][d])
    float* km  = kv + 128 * 1024;                     // 2,048
    unsigned short* xb = (unsigned short*)(km + 2048);        // bf16 x
    unsigned short* Wb = xb + (size_t)M_ROWS * C_DIM;         // bf16 W
    float* lut = (float*)(Wb + (size_t)QK_COLS * C_DIM);      // 16384 + 512 floats
    float* kW  = out;   // k staged in d_out; consumed before pass 4 writes
    float* nrmP = kvp;  // norm partials alias kvp (gemm/norm_fin finish
                        // before kv_partial writes kvp — stream-ordered)

    prep_kernel<<<16928, 256, 0, stream>>>(x, Wqk, scale_p, xb, Wb, lut);

    dim3 gg(QK_COLS / GBN, M_ROWS / GBM);
    gemm_mfma_kernel<<<gg, 256, 0, stream>>>(xb, Wb, bqk, lut, qW, kW, nrmP);

    norm_fin_kernel<<<128, 256, 0, stream>>>(nrmP, sq, sk);

    kv_partial_kernel<<<128 * NSPLIT, 256, 0, stream>>>(x, kW, sk, kvp, kmp);
    kv_reduce_kernel<<<128, 256, 0, stream>>>(kvp, kmp, kv, km);

    dim3 g4(128, 32);
    attn_conv_kernel<<<g4, 256, 0, stream>>>(qW, sq, kv, km, x, dwc_w, dwc_b, out);
}

// Round 9
// 319.071 us; speedup vs baseline: 1.0548x; 1.0548x over previous
//
#include <hip/hip_runtime.h>
#include <math.h>

// Problem constants (fixed by setup_inputs)
#define B_SZ 8
#define IMG_H 64
#define IMG_W 64
#define N_TOK 4096          // 64*64
#define C_DIM 512
#define HEADS 16
#define HDIM 32
#define M_ROWS (B_SZ * N_TOK)   // 32768
#define QK_COLS (2 * C_DIM)     // 1024

// theta coefficient: -ln(10000)/128
#define THETA_COEF (-0.07195578415606394f)

typedef __attribute__((ext_vector_type(8))) __bf16 bf16x8;
typedef __attribute__((ext_vector_type(4))) float f32x4;

__device__ __forceinline__ void async_ld16(void* lds, const void* g) {
    __builtin_amdgcn_global_load_lds(
        (const __attribute__((address_space(1))) unsigned*)g,
        (__attribute__((address_space(3))) unsigned*)lds, 16, 0, 0);
}

__device__ __forceinline__ unsigned short f2bf(float f) {
    unsigned u = __float_as_uint(f);
    u += 0x7FFF + ((u >> 16) & 1);   // round-to-nearest-even (finite inputs)
    return (unsigned short)(u >> 16);
}

// ---------------------------------------------------------------------------
// Pass 0 (merged): fp32->bf16 for x (blocks 0..16383) and Wqk (..16895),
// RoPE cos/sin LUT + rsp table (..16927).
// ---------------------------------------------------------------------------
__global__ __launch_bounds__(256) void prep_kernel(
    const float* __restrict__ x, const float* __restrict__ Wqk,
    const float* __restrict__ scale_p,
    unsigned short* __restrict__ xb, unsigned short* __restrict__ Wb,
    float* __restrict__ lut)
{
    int bid = blockIdx.x;
    int t = threadIdx.x;
    if (bid < 16384) {
        int i = bid * 256 + t;
        float4 v = ((const float4*)x)[i];
        ushort4 o;
        o.x = f2bf(v.x); o.y = f2bf(v.y); o.z = f2bf(v.z); o.w = f2bf(v.w);
        ((ushort4*)xb)[i] = o;
    } else if (bid < 16896) {
        int i = (bid - 16384) * 256 + t;
        float4 v = ((const float4*)Wqk)[i];
        ushort4 o;
        o.x = f2bf(v.x); o.y = f2bf(v.y); o.z = f2bf(v.z); o.w = f2bf(v.w);
        ((ushort4*)Wb)[i] = o;
    } else {
        int idx = (bid - 16896) * 256 + t;   // 8192
        int pos = idx >> 7, tt = idx & 127;
        float theta = expf((float)tt * THETA_COEF);
        float ang = (float)pos * theta;
        lut[idx] = cosf(ang);
        lut[idx + 8192] = sinf(ang);
        if (idx < 512) lut[16384 + idx] = 1.0f / log1pf(expf(scale_p[idx]));
    }
}

// ---------------------------------------------------------------------------
// Pass 1: qk = x @ W^T + b (bf16 MFMA), fused RoPE + (elu+1) + /softplus(scale)
// GBK=32 geometry (0 conflicts) + 2-phase double-buffer. At the m97-structure
// ceiling (~69 µs). r8's fused-norm epilogue was net-neutral -> reverted.
// ---------------------------------------------------------------------------
#define GBM 128
#define GBN 128
#define GBK 32

#define EPI_I(I, ACC) do {                                                    \
    float cr = cI, sr = sI;                                                   \
    _Pragma("unroll")                                                         \
    for (int r = 0; r < 4; ++r) {                                             \
        int m = m0 + wm + (I) * 16 + quad * 4 + r;                            \
        float val = (ACC)[r] + bias;                                          \
        float oth = __shfl_xor(val, 1);                                       \
        float rot = is_im ? (val * cr + oth * sr) : (val * cr - oth * sr);    \
        rot = (rot > 0.f) ? (rot + 1.f) : __expf(rot);                        \
        dst[(size_t)m * C_DIM + ch] = rot * rspv;                             \
        float tc = cr * c1 - sr * s1, ts = sr * c1 + cr * s1;                 \
        cr = tc; sr = ts;                                                     \
    }                                                                         \
    float uc = cI * c16 - sI * s16, us = sI * c16 + cI * s16;                 \
    cI = uc; sI = us;                                                         \
} while (0)

#define EPI_J(J, A0, A1, A2, A3) do {                                         \
    int c = n0 + wn + (J) * 16 + l16;                                         \
    int ch = c & 511;                                                         \
    float bias = bqk[c];                                                      \
    float rspv = rsp[ch];                                                     \
    int tt = ch >> 1;                                                         \
    int tl = tt & 127;                                                        \
    float cI, sI, c1, s1, c16, s16;                                           \
    if (tt < 128) {      /* block-uniform branch; pos wave-uniform */         \
        int pos = ((m0 + wm) & (N_TOK - 1)) >> 6;                             \
        cI = lut[pos * 128 + tl]; sI = lut[pos * 128 + tl + 8192];            \
        c1 = 1.f; s1 = 0.f; c16 = 1.f; s16 = 0.f;                             \
    } else {             /* pos = I*16 + quad*4 + r: rotate from seeds */     \
        int pos0 = quad * 4;                                                  \
        cI = lut[pos0 * 128 + tl]; sI = lut[pos0 * 128 + tl + 8192];          \
        c1  = lut[128 + tl];       s1  = lut[128 + tl + 8192];                \
        c16 = lut[2048 + tl];      s16 = lut[2048 + tl + 8192];               \
    }                                                                         \
    float* dst = (c < C_DIM) ? qW : kW;                                       \
    EPI_I(0, A0); EPI_I(1, A1); EPI_I(2, A2); EPI_I(3, A3);                   \
} while (0)

__global__ __launch_bounds__(256, 1) void gemm_mfma_kernel(
    const unsigned short* __restrict__ xb,   // (32768,512) bf16
    const unsigned short* __restrict__ Wb,   // (1024,512) bf16
    const float* __restrict__ bqk,           // (1024)
    const float* __restrict__ lut,           // cos/sin LUT + rsp table
    float* __restrict__ qW,                  // (32768,512)
    float* __restrict__ kW)                  // (32768,512)
{
    __shared__ char lds[32768];

    const float* rsp = lut + 16384;

    const int t = threadIdx.x;
    const int wave = t >> 6;
    const int lane = t & 63;
    const int quad = lane >> 4;
    const int l16 = lane & 15;
    const int is_im = l16 & 1;

    const int flat = blockIdx.x + 8 * blockIdx.y;
    const int xcd = flat & 7;
    const int ii_ = flat >> 3;
    const int n0 = (ii_ & 7) * GBN;
    const int m0 = (xcd * 32 + (ii_ >> 3)) * GBM;

    const int wm = (wave >> 1) * 64;
    const int wn = (wave & 1) * 64;

    const int srow = t >> 2;
    const int sj = t & 3;

    f32x4 acc00 = {0.f,0.f,0.f,0.f}, acc01 = {0.f,0.f,0.f,0.f},
          acc02 = {0.f,0.f,0.f,0.f}, acc03 = {0.f,0.f,0.f,0.f},
          acc10 = {0.f,0.f,0.f,0.f}, acc11 = {0.f,0.f,0.f,0.f},
          acc12 = {0.f,0.f,0.f,0.f}, acc13 = {0.f,0.f,0.f,0.f},
          acc20 = {0.f,0.f,0.f,0.f}, acc21 = {0.f,0.f,0.f,0.f},
          acc22 = {0.f,0.f,0.f,0.f}, acc23 = {0.f,0.f,0.f,0.f},
          acc30 = {0.f,0.f,0.f,0.f}, acc31 = {0.f,0.f,0.f,0.f},
          acc32 = {0.f,0.f,0.f,0.f}, acc33 = {0.f,0.f,0.f,0.f};

    const int swz = (l16 >> 1) & 3;
    const int co = (quad ^ swz) * 16;

    auto stage = [&](int k0, int b) {
#pragma unroll
        for (int p = 0; p < 2; ++p) {
            int m = p * 64 + srow;
            int jp = sj ^ ((m >> 1) & 3);
            const unsigned short* ga = xb + (size_t)(m0 + m) * C_DIM + k0 + jp * 8;
            async_ld16(lds + b * 16384 + p * 4096 + wave * 1024, ga);
            const unsigned short* gb = Wb + (size_t)(n0 + m) * C_DIM + k0 + jp * 8;
            async_ld16(lds + b * 16384 + 8192 + p * 4096 + wave * 1024, gb);
        }
    };

    stage(0, 0);
    __syncthreads();
    int buf = 0;

    for (int k0 = 0; k0 < C_DIM; k0 += GBK) {
        if (k0 + GBK < C_DIM) stage(k0 + GBK, buf ^ 1);

        const char* As = lds + buf * 16384;
        const char* Bs = As + 8192;
        bf16x8 a0 = *(const bf16x8*)(As + (wm + 0 * 16 + l16) * 64 + co);
        bf16x8 a1 = *(const bf16x8*)(As + (wm + 1 * 16 + l16) * 64 + co);
        bf16x8 a2 = *(const bf16x8*)(As + (wm + 2 * 16 + l16) * 64 + co);
        bf16x8 a3 = *(const bf16x8*)(As + (wm + 3 * 16 + l16) * 64 + co);
        bf16x8 b0 = *(const bf16x8*)(Bs + (wn + 0 * 16 + l16) * 64 + co);
        bf16x8 b1 = *(const bf16x8*)(Bs + (wn + 1 * 16 + l16) * 64 + co);
        bf16x8 b2 = *(const bf16x8*)(Bs + (wn + 2 * 16 + l16) * 64 + co);
        bf16x8 b3 = *(const bf16x8*)(Bs + (wn + 3 * 16 + l16) * 64 + co);

        acc00 = __builtin_amdgcn_mfma_f32_16x16x32_bf16(a0, b0, acc00, 0, 0, 0);
        acc01 = __builtin_amdgcn_mfma_f32_16x16x32_bf16(a0, b1, acc01, 0, 0, 0);
        acc02 = __builtin_amdgcn_mfma_f32_16x16x32_bf16(a0, b2, acc02, 0, 0, 0);
        acc03 = __builtin_amdgcn_mfma_f32_16x16x32_bf16(a0, b3, acc03, 0, 0, 0);
        acc10 = __builtin_amdgcn_mfma_f32_16x16x32_bf16(a1, b0, acc10, 0, 0, 0);
        acc11 = __builtin_amdgcn_mfma_f32_16x16x32_bf16(a1, b1, acc11, 0, 0, 0);
        acc12 = __builtin_amdgcn_mfma_f32_16x16x32_bf16(a1, b2, acc12, 0, 0, 0);
        acc13 = __builtin_amdgcn_mfma_f32_16x16x32_bf16(a1, b3, acc13, 0, 0, 0);
        acc20 = __builtin_amdgcn_mfma_f32_16x16x32_bf16(a2, b0, acc20, 0, 0, 0);
        acc21 = __builtin_amdgcn_mfma_f32_16x16x32_bf16(a2, b1, acc21, 0, 0, 0);
        acc22 = __builtin_amdgcn_mfma_f32_16x16x32_bf16(a2, b2, acc22, 0, 0, 0);
        acc23 = __builtin_amdgcn_mfma_f32_16x16x32_bf16(a2, b3, acc23, 0, 0, 0);
        acc30 = __builtin_amdgcn_mfma_f32_16x16x32_bf16(a3, b0, acc30, 0, 0, 0);
        acc31 = __builtin_amdgcn_mfma_f32_16x16x32_bf16(a3, b1, acc31, 0, 0, 0);
        acc32 = __builtin_amdgcn_mfma_f32_16x16x32_bf16(a3, b2, acc32, 0, 0, 0);
        acc33 = __builtin_amdgcn_mfma_f32_16x16x32_bf16(a3, b3, acc33, 0, 0, 0);

        __syncthreads();
        buf ^= 1;
    }

    EPI_J(0, acc00, acc10, acc20, acc30);
    EPI_J(1, acc01, acc11, acc21, acc31);
    EPI_J(2, acc02, acc12, acc22, acc32);
    EPI_J(3, acc03, acc13, acc23, acc33);
}

// ---------------------------------------------------------------------------
// Pass 2: per-row norms -> s = ||v|| / ||v^3||  (for q and k), float4 loads
// ---------------------------------------------------------------------------
__global__ __launch_bounds__(256) void norm_kernel(
    const float* __restrict__ qW, const float* __restrict__ kW,
    float* __restrict__ sq, float* __restrict__ sk)
{
    int wave = threadIdx.x >> 6;
    int lane = threadIdx.x & 63;
    int m = blockIdx.x * 4 + wave;
    const float4* qr = (const float4*)(qW + (size_t)m * C_DIM);
    const float4* kr = (const float4*)(kW + (size_t)m * C_DIM);
    float q2 = 0.f, q6 = 0.f, k2 = 0.f, k6 = 0.f;
#pragma unroll
    for (int l = 0; l < 2; ++l) {
        float4 q4 = qr[lane + l * 64];
        float4 k4 = kr[lane + l * 64];
        float qq;
        qq = q4.x * q4.x; q2 += qq; q6 += qq * qq * qq;
        qq = q4.y * q4.y; q2 += qq; q6 += qq * qq * qq;
        qq = q4.z * q4.z; q2 += qq; q6 += qq * qq * qq;
        qq = q4.w * q4.w; q2 += qq; q6 += qq * qq * qq;
        qq = k4.x * k4.x; k2 += qq; k6 += qq * qq * qq;
        qq = k4.y * k4.y; k2 += qq; k6 += qq * qq * qq;
        qq = k4.z * k4.z; k2 += qq; k6 += qq * qq * qq;
        qq = k4.w * k4.w; k2 += qq; k6 += qq * qq * qq;
    }
#pragma unroll
    for (int off = 32; off > 0; off >>= 1) {
        q2 += __shfl_down(q2, off);
        q6 += __shfl_down(q6, off);
        k2 += __shfl_down(k2, off);
        k6 += __shfl_down(k6, off);
    }
    if (lane == 0) {
        sq[m] = sqrtf(q2) / sqrtf(q6);
        sk[m] = sqrtf(k2) / sqrtf(k6);
    }
}

// ---------------------------------------------------------------------------
// Pass 3a: partial kv[d][e] = sum_n k_f[n,d]*v[n,e] and km[d] = sum_n k_f[n,d]
// v4: DOUBLE-BUFFERED kf/vv -> ONE barrier per 64-row tile (was 2). WAR safe:
// a wave writes buf[tt&1] only after passing barrier tt-1, which waits for
// all readers of tile tt-2 (same buffer). Zero VGPR cost.
// ---------------------------------------------------------------------------
#define NSPLIT 8
#define ROWS_PER_SPLIT (N_TOK / NSPLIT)   // 512

__global__ __launch_bounds__(256) void kv_partial_kernel(
    const float* __restrict__ x, const float* __restrict__ kW,
    const float* __restrict__ sk,
    float* __restrict__ kvp, float* __restrict__ kmp)
{
    int g = blockIdx.x >> 3;       // (b*16+h)
    int split = blockIdx.x & 7;
    int b = g >> 4, h = g & 15;
    int n_start = split * ROWS_PER_SPLIT;

    __shared__ float smem[9216];   // 2 bufs x (kf[64][36] | vv[64][36])

    int t = threadIdx.x;
    int wave = t >> 6, lane = t & 63;
    int srow = t >> 3;
    int scol = (t & 7) * 4;
    int d0 = (lane >> 3) * 4;
    int e0 = (lane & 7) * 4;

    float acc[4][4] = {{0.f}};
    float4 kmacc = make_float4(0.f, 0.f, 0.f, 0.f);

    float4 kreg[2], vreg[2];
    float sreg[2];
#pragma unroll
    for (int h2 = 0; h2 < 2; ++h2) {
        int n = n_start + h2 * 32 + srow;
        size_t base = ((size_t)(b * N_TOK + n)) * C_DIM + h * HDIM + scol;
        kreg[h2] = *(const float4*)&kW[base];
        vreg[h2] = *(const float4*)&x[base];
        sreg[h2] = sk[b * N_TOK + n];
    }

    for (int tt = 0; tt < ROWS_PER_SPLIT / 64; ++tt) {
        float* kf = smem + (tt & 1) * 4608;
        float* vv = kf + 2304;
#pragma unroll
        for (int h2 = 0; h2 < 2; ++h2) {
            int row = h2 * 32 + srow;
            float4 k4 = kreg[h2];
            float s = sreg[h2];
            float4 k3;
            k3.x = k4.x * k4.x * k4.x * s;
            k3.y = k4.y * k4.y * k4.y * s;
            k3.z = k4.z * k4.z * k4.z * s;
            k3.w = k4.w * k4.w * k4.w * s;
            *(float4*)&kf[row * 36 + scol] = k3;
            *(float4*)&vv[row * 36 + scol] = vreg[h2];
            kmacc.x += k3.x; kmacc.y += k3.y;
            kmacc.z += k3.z; kmacc.w += k3.w;
        }
        if (tt < ROWS_PER_SPLIT / 64 - 1) {   // prefetch next tile's regs
            int nb = n_start + (tt + 1) * 64;
#pragma unroll
            for (int h2 = 0; h2 < 2; ++h2) {
                int n = nb + h2 * 32 + srow;
                size_t base = ((size_t)(b * N_TOK + n)) * C_DIM + h * HDIM + scol;
                kreg[h2] = *(const float4*)&kW[base];
                vreg[h2] = *(const float4*)&x[base];
                sreg[h2] = sk[b * N_TOK + n];
            }
        }
        __syncthreads();   // staging of buf[tt&1] visible; prior readers done

        const float* kfp = kf + (wave * 16) * 36 + d0;
        const float* vvp = vv + (wave * 16) * 36 + e0;
#pragma unroll
        for (int nn = 0; nn < 16; ++nn) {
            float4 k4 = *(const float4*)(kfp + nn * 36);
            float4 v4 = *(const float4*)(vvp + nn * 36);
            acc[0][0] += k4.x * v4.x; acc[0][1] += k4.x * v4.y;
            acc[0][2] += k4.x * v4.z; acc[0][3] += k4.x * v4.w;
            acc[1][0] += k4.y * v4.x; acc[1][1] += k4.y * v4.y;
            acc[1][2] += k4.y * v4.z; acc[1][3] += k4.y * v4.w;
            acc[2][0] += k4.z * v4.x; acc[2][1] += k4.z * v4.y;
            acc[2][2] += k4.z * v4.z; acc[2][3] += k4.z * v4.w;
            acc[3][0] += k4.w * v4.x; acc[3][1] += k4.w * v4.y;
            acc[3][2] += k4.w * v4.z; acc[3][3] += k4.w * v4.w;
        }
    }

    __syncthreads();                   // all tile reads done; reuse smem
    float* red = smem;                 // [4][32*32] laid out d*32+e
    float* kmr = smem + 4096;          // [32][32]
#pragma unroll
    for (int di = 0; di < 4; ++di) {
        float4 v = make_float4(acc[di][0], acc[di][1], acc[di][2], acc[di][3]);
        *(float4*)&red[wave * 1024 + (d0 + di) * 32 + e0] = v;
    }
    *(float4*)&kmr[srow * 32 + scol] = kmacc;
    __syncthreads();

    size_t pbase = (size_t)blockIdx.x * 1024;
    for (int idx = t; idx < 1024; idx += 256) {
        float s = red[idx] + red[1024 + idx] + red[2048 + idx] + red[3072 + idx];
        kvp[pbase + idx] = s;
    }
    if (t < 32) {
        float s = 0.f;
#pragma unroll
        for (int r = 0; r < 32; ++r) s += kmr[r * 32 + t];
        kmp[blockIdx.x * 32 + t] = s;
    }
}

// Pass 3b: reduce the 8 splits; scale by 1/N. kv written TRANSPOSED [g][e][d].
__global__ __launch_bounds__(256) void kv_reduce_kernel(
    const float* __restrict__ kvp, const float* __restrict__ kmp,
    float* __restrict__ kv, float* __restrict__ km)
{
    int g = blockIdx.x;   // 128
    int t = threadIdx.x;
    for (int idx = t; idx < 1024; idx += 256) {
        float s = 0.f;
#pragma unroll
        for (int sp = 0; sp < NSPLIT; ++sp)
            s += kvp[((size_t)(g * NSPLIT + sp)) * 1024 + idx];
        int d = idx >> 5, e = idx & 31;
        kv[(size_t)g * 1024 + e * 32 + d] = s * (1.0f / 4096.0f);
    }
    if (t < 32) {
        float s = 0.f;
#pragma unroll
        for (int sp = 0; sp < NSPLIT; ++sp) s += kmp[(g * NSPLIT + sp) * 32 + t];
        km[g * 32 + t] = s * (1.0f / 4096.0f);
    }
}

// ---------------------------------------------------------------------------
// Pass 4 (FUSED attn + depthwise conv). v3: conv phase identical to the
// r7/56-VGPR version (r8's pipelining regressed: VGPR 124, occupancy halved).
// Phase A now DOUBLE-BUFFERS qf -> ONE barrier per chunk (was 2); same WAR
// proof as kv_partial. 8 barriers removed per block, zero VGPR cost.
// ---------------------------------------------------------------------------
__global__ __launch_bounds__(256) void attn_conv_kernel(
    const float* __restrict__ qW, const float* __restrict__ sq,
    const float* __restrict__ kvT, const float* __restrict__ km,
    const float* __restrict__ x, const float* __restrict__ w,
    const float* __restrict__ wbias, float* __restrict__ out)
{
    int g = blockIdx.x;           // b*16 + h
    int b = g >> 4, h = g & 15;
    int n0 = blockIdx.y * 128;

    __shared__ float qf[2][16][36];  // double-buffered q staging
    __shared__ float ob[128][34];    // attn results
    __shared__ float wl[25][32];

    int t = threadIdx.x;
    for (int idx = t; idx < 800; idx += 256) {   // conv weights, once
        int o = idx & 31, tap = idx >> 5;
        wl[tap][o] = w[o * 25 + tap];
    }

    int e = t & 15;               // e-lane (handles e and e+16)
    int nl = t >> 4;              // row within 16-row chunk
    int sd = e * 2;               // staging d-pair

    const float* kvg = kvT + (size_t)g * 1024;
    float4 kva[8], kvb[8], kmr[8];
#pragma unroll
    for (int j = 0; j < 8; ++j) {
        kva[j] = *(const float4*)&kvg[e * 32 + j * 4];
        kvb[j] = *(const float4*)&kvg[(e + 16) * 32 + j * 4];
        kmr[j] = *(const float4*)&km[g * 32 + j * 4];
    }

    size_t rbase = ((size_t)(b * N_TOK + n0 + nl)) * C_DIM + h * HDIM;

    float2 q2 = *(const float2*)&qW[rbase + sd];
    float sv = sq[b * N_TOK + n0 + nl];

    for (int ch = 0; ch < 8; ++ch) {
        *(float2*)&qf[ch & 1][nl][sd] =
            make_float2(q2.x * q2.x * q2.x * sv, q2.y * q2.y * q2.y * sv);

        float2 q2n; float svn;
        if (ch < 7) {             // issue next chunk's loads before the barrier
            size_t nb = rbase + (size_t)(ch + 1) * 16 * C_DIM;
            q2n = *(const float2*)&qW[nb + sd];
            svn = sq[b * N_TOK + n0 + (ch + 1) * 16 + nl];
        }
        __syncthreads();          // buf[ch&1] visible; chunk ch-2 readers done

        float s1a = 0.f, s1b = 0.f, s2 = 0.f;
#pragma unroll
        for (int j = 0; j < 8; ++j) {
            float4 q4 = *(const float4*)&qf[ch & 1][nl][j * 4];
            s1a += q4.x * kva[j].x + q4.y * kva[j].y
                 + q4.z * kva[j].z + q4.w * kva[j].w;
            s1b += q4.x * kvb[j].x + q4.y * kvb[j].y
                 + q4.z * kvb[j].z + q4.w * kvb[j].w;
            s2  += q4.x * kmr[j].x + q4.y * kmr[j].y
                 + q4.z * kmr[j].z + q4.w * kmr[j].w;
        }
        float z = 1.0f / (s2 + 1e-6f);
        ob[ch * 16 + nl][e] = s1a * z;
        ob[ch * 16 + nl][e + 16] = s1b * z;

        if (ch < 7) { q2 = q2n; sv = svn; }
    }

    __syncthreads();              // ob + wl complete

    // ---- Phase B: depthwise conv 5x5 (r7 geometry, 56-VGPR version) ----
    int r = t >> 7;               // image row within block (wave-uniform)
    int jg = (t >> 3) & 15;       // j-group of 4
    int cg = t & 7;               // channel-group of 4 (within head)
    int j0 = jg * 4;
    int o4 = cg * 4;
    int i = (n0 >> 6) + r;        // global image row

    const float* xbase = x + ((size_t)b * N_TOK) * C_DIM + h * HDIM + o4;

    float4 b4 = *(const float4*)&wbias[o4];
    float4 acc[4] = {b4, b4, b4, b4};

#pragma unroll
    for (int ki = 0; ki < 5; ++ki) {
        int ii = i + ki - 2;
        if (ii < 0 || ii >= IMG_H) continue;      // wave-uniform
        const float* xr = xbase + (size_t)ii * 64 * C_DIM;
        float4 row[8];
#pragma unroll
        for (int jx = 0; jx < 8; ++jx) {
            int jj = j0 + jx - 2;
            row[jx] = (jj >= 0 && jj < IMG_W)
                          ? *(const float4*)(xr + (size_t)jj * C_DIM)
                          : make_float4(0.f, 0.f, 0.f, 0.f);
        }
#pragma unroll
        for (int kj = 0; kj < 5; ++kj) {
            float4 w4 = *(const float4*)&wl[ki * 5 + kj][o4];
#pragma unroll
            for (int jo = 0; jo < 4; ++jo) {
                acc[jo].x += w4.x * row[jo + kj].x;
                acc[jo].y += w4.y * row[jo + kj].y;
                acc[jo].z += w4.z * row[jo + kj].z;
                acc[jo].w += w4.w * row[jo + kj].w;
            }
        }
    }

    float* op = out + ((size_t)(b * N_TOK + i * 64 + j0)) * C_DIM + h * HDIM + o4;
#pragma unroll
    for (int jo = 0; jo < 4; ++jo) {
        float4 a = *(const float4*)&ob[r * 64 + j0 + jo][o4];
        acc[jo].x += a.x;
        acc[jo].y += a.y;
        acc[jo].z += a.z;
        acc[jo].w += a.w;
        *(float4*)(op + (size_t)jo * C_DIM) = acc[jo];
    }
}

// ---------------------------------------------------------------------------
extern "C" void kernel_launch(void* const* d_in, const int* in_sizes, int n_in,
                              void* d_out, int out_size, void* d_ws, size_t ws_size,
                              hipStream_t stream) {
    const float* x       = (const float*)d_in[0];
    const float* Wqk     = (const float*)d_in[1];
    const float* bqk     = (const float*)d_in[2];
    const float* scale_p = (const float*)d_in[3];
    const float* dwc_w   = (const float*)d_in[4];
    const float* dwc_b   = (const float*)d_in[5];
    float* out = (float*)d_out;
    float* ws = (float*)d_ws;

    // workspace layout (floats): qW | sq | sk | kvp | kmp | kv | km | xb | Wb | lut
    float* qW  = ws;                                  // 16,777,216
    float* sq  = qW + (size_t)M_ROWS * C_DIM;         // 32,768
    float* sk  = sq + M_ROWS;                         // 32,768
    float* kvp = sk + M_ROWS;                         // 1,048,576
    float* kmp = kvp + (size_t)1024 * 1024;           // 32,768
    float* kv  = kmp + 1024 * 32;                     // 131,072 (transposed [g][e][d])
    float* km  = kv + 128 * 1024;                     // 2,048
    unsigned short* xb = (unsigned short*)(km + 2048);        // bf16 x
    unsigned short* Wb = xb + (size_t)M_ROWS * C_DIM;         // bf16 W
    float* lut = (float*)(Wb + (size_t)QK_COLS * C_DIM);      // 16384 + 512 floats
    float* kW  = out;   // k staged in d_out; consumed before pass 4 writes

    prep_kernel<<<16928, 256, 0, stream>>>(x, Wqk, scale_p, xb, Wb, lut);

    dim3 gg(QK_COLS / GBN, M_ROWS / GBM);
    gemm_mfma_kernel<<<gg, 256, 0, stream>>>(xb, Wb, bqk, lut, qW, kW);

    norm_kernel<<<M_ROWS / 4, 256, 0, stream>>>(qW, kW, sq, sk);

    kv_partial_kernel<<<128 * NSPLIT, 256, 0, stream>>>(x, kW, sk, kvp, kmp);
    kv_reduce_kernel<<<128, 256, 0, stream>>>(kvp, kmp, kv, km);

    dim3 g4(128, 32);
    attn_conv_kernel<<<g4, 256, 0, stream>>>(qW, sq, kv, km, x, dwc_w, dwc_b, out);
}